// Round 1
// baseline (1158.349 us; speedup 1.0000x reference)
//
#include <hip/hip_runtime.h>

#define GAMMA 0.01f
#define INV_GAMMA 100.0f
#define B 32
#define G 2048
#define C 16
#define S 8
#define L 3
#define M 16
#define GT 256          // g-tile per block
#define NGT (G / GT)    // 8

__device__ __forceinline__ void atomicMaxF(float* addr, float v) {
    // standard two-branch float atomic max (works for mixed signs)
    if (v >= 0.f) atomicMax((int*)addr, __float_as_int(v));
    else          atomicMin((unsigned int*)addr, __float_as_uint(v));
}

__device__ __forceinline__ float waveMax(float v) {
#pragma unroll
    for (int off = 32; off > 0; off >>= 1)
        v = fmaxf(v, __shfl_xor(v, off, 64));
    return v;
}

// One-time: Ws = softmax(W, axis=1); init the 15 global-max scalars to -inf.
__global__ void kinit(const float* __restrict__ W, float* __restrict__ Ws,
                      float* __restrict__ mx) {
    int t = threadIdx.x;           // 256 threads
    if (t < 16) mx[t] = -INFINITY;
    int m = t >> 4, c = t & 15;
    float rmax = -INFINITY;
#pragma unroll
    for (int j = 0; j < C; j++) rmax = fmaxf(rmax, W[m * C + j]);
    float rsum = 0.f;
#pragma unroll
    for (int j = 0; j < C; j++) rsum += __expf(W[m * C + j] - rmax);
    Ws[m * C + c] = __expf(W[m * C + c] - rmax) / rsum;
}

// K1: Cv_y[b,c,g] = gamma*lse_s( prod_l V[b, I[c,g,s,l]] / gamma ); atomicMax -> mx1
// V[b,g] = scale * Vsrc[b,g], scale = (mx3_prev > 1 ? 1/mx3_prev : 1)
__global__ __launch_bounds__(256) void k1(
    const float* __restrict__ Vsrc, const float* __restrict__ scale_ptr,
    const int* __restrict__ I, float* __restrict__ Cv, float* __restrict__ mx1) {
    __shared__ float Vrow[G];      // 8 KB: row b of V, pre-scaled
    const int b = blockIdx.z, c = blockIdx.y, gt = blockIdx.x;
    const int t = threadIdx.x;

    float s = 1.0f;
    if (scale_ptr) { float m = *scale_ptr; s = (m > 1.0f) ? 1.0f / m : 1.0f; }

    const float4* V4 = (const float4*)(Vsrc + (size_t)b * G);
    float4* Vr4 = (float4*)Vrow;
#pragma unroll
    for (int j = 0; j < G / 4 / 256; j++) {   // 2 iters
        float4 v = V4[t + j * 256];
        v.x *= s; v.y *= s; v.z *= s; v.w *= s;
        Vr4[t + j * 256] = v;
    }
    __syncthreads();

    const int g = gt * GT + t;
    const int4* ip = (const int4*)(I + ((size_t)c * G + g) * (S * L));
    int idx[S * L];
#pragma unroll
    for (int j = 0; j < 6; j++) {
        int4 v = ip[j];
        idx[j * 4 + 0] = v.x; idx[j * 4 + 1] = v.y;
        idx[j * 4 + 2] = v.z; idx[j * 4 + 3] = v.w;
    }
    float body[S];
#pragma unroll
    for (int ss = 0; ss < S; ss++)
        body[ss] = Vrow[idx[ss * 3]] * Vrow[idx[ss * 3 + 1]] * Vrow[idx[ss * 3 + 2]];

    float bm = body[0];
#pragma unroll
    for (int ss = 1; ss < S; ss++) bm = fmaxf(bm, body[ss]);
    float sum = 0.f;
#pragma unroll
    for (int ss = 0; ss < S; ss++) sum += __expf((body[ss] - bm) * INV_GAMMA);
    float y = bm + GAMMA * __logf(sum);

    Cv[((size_t)b * C + c) * G + g] = y;
    float wm = waveMax(y);
    if ((t & 63) == 0) atomicMaxF(mx1, wm);
}

// K2: H[m] = sum_c Ws[m,c] * (s1*Cv[b,c,g]); Hy = gamma*lse_m(H/gamma); atomicMax -> mx2
__global__ __launch_bounds__(256) void k2(
    const float* __restrict__ Cv, const float* __restrict__ Ws,
    const float* __restrict__ mx1, float* __restrict__ Hy, float* __restrict__ mx2) {
    __shared__ float CvL[C][GT];   // 16 KB
    __shared__ float WsL[M * C];   // 1 KB
    const int b = blockIdx.y, gt = blockIdx.x, t = threadIdx.x;

    float m1 = *mx1;
    float s1 = (m1 > 1.0f) ? 1.0f / m1 : 1.0f;
    WsL[t] = Ws[t];                // 256 == M*C
    const int g = gt * GT + t;
#pragma unroll
    for (int c = 0; c < C; c++)
        CvL[c][t] = s1 * Cv[((size_t)b * C + c) * G + g];
    __syncthreads();

    float cv[C];
#pragma unroll
    for (int c = 0; c < C; c++) cv[c] = CvL[c][t];

    float h[M];
    float hm = -INFINITY;
#pragma unroll
    for (int m = 0; m < M; m++) {
        float acc = 0.f;
#pragma unroll
        for (int c = 0; c < C; c++) acc = fmaf(WsL[m * C + c], cv[c], acc);
        h[m] = acc; hm = fmaxf(hm, acc);
    }
    float sum = 0.f;
#pragma unroll
    for (int m = 0; m < M; m++) sum += __expf((h[m] - hm) * INV_GAMMA);
    float y = hm + GAMMA * __logf(sum);

    Hy[(size_t)b * G + g] = y;
    float wm = waveMax(y);
    if ((t & 63) == 0) atomicMaxF(mx2, wm);
}

// K3: R_new_y = gamma*lse_2(R_prev, s2*Hy); atomicMax -> mx3. (in-place safe; src may be x)
__global__ __launch_bounds__(256) void k3(
    const float* __restrict__ Rprev, const float* __restrict__ scale_prev,
    const float* __restrict__ Hy, const float* __restrict__ mx2,
    float* __restrict__ Ry, float* __restrict__ mx3) {
    const int i = blockIdx.x * 256 + threadIdx.x;  // over B*G
    float sp = 1.0f;
    if (scale_prev) { float m = *scale_prev; sp = (m > 1.0f) ? 1.0f / m : 1.0f; }
    float m2 = *mx2;
    float s2 = (m2 > 1.0f) ? 1.0f / m2 : 1.0f;
    float Rv = sp * Rprev[i];
    float rv = s2 * Hy[i];
    float a = fmaxf(Rv, rv), d = fminf(Rv, rv);
    float y = a + GAMMA * __logf(1.0f + __expf((d - a) * INV_GAMMA));
    Ry[i] = y;
    float wm = waveMax(y);
    if ((threadIdx.x & 63) == 0) atomicMaxF(mx3, wm);
}

__global__ void kout(const float* __restrict__ Ry, const float* __restrict__ mx3,
                     float* __restrict__ out) {
    const int i = blockIdx.x * 256 + threadIdx.x;
    float m = *mx3;
    float s = (m > 1.0f) ? 1.0f / m : 1.0f;
    out[i] = s * Ry[i];
}

extern "C" void kernel_launch(void* const* d_in, const int* in_sizes, int n_in,
                              void* d_out, int out_size, void* d_ws, size_t ws_size,
                              hipStream_t stream) {
    const float* x = (const float*)d_in[0];   // (B,G)
    const float* W = (const float*)d_in[1];   // (M,C)
    const int*   I = (const int*)d_in[2];     // (C,G,S,L)
    float* out = (float*)d_out;

    float* ws  = (float*)d_ws;
    float* Ws  = ws;                      // 256
    float* mx  = ws + 256;                // 16 scalars (15 used)
    float* Cv  = ws + 512;                // B*C*G = 1,048,576
    float* Hy  = Cv + (size_t)B * C * G;  // B*G
    float* Ry  = Hy + (size_t)B * G;      // B*G

    kinit<<<1, 256, 0, stream>>>(W, Ws, mx);

    const float* V = x;
    const float* vscale = nullptr;
    for (int it = 0; it < 5; it++) {
        float* m1 = mx + it * 3 + 0;
        float* m2 = mx + it * 3 + 1;
        float* m3 = mx + it * 3 + 2;
        k1<<<dim3(NGT, C, B), 256, 0, stream>>>(V, vscale, I, Cv, m1);
        k2<<<dim3(NGT, B), 256, 0, stream>>>(Cv, Ws, m1, Hy, m2);
        k3<<<dim3((B * G) / 256), 256, 0, stream>>>(V, vscale, Hy, m2, Ry, m3);
        V = Ry;
        vscale = m3;
    }
    kout<<<(B * G) / 256, 256, 0, stream>>>(Ry, mx + 4 * 3 + 2, out);
}

// Round 2
// 143.581 us; speedup vs baseline: 8.0676x; 8.0676x over previous
//
#include <hip/hip_runtime.h>

#define GAMMA 0.01f
#define INV_GAMMA 100.0f
#define B 32
#define G 2048
#define C 16
#define S 8
#define L 3
#define M 16
#define NGT 8           // g-tiles of 256
#define NCG 2           // c-groups of 8

__device__ __forceinline__ float waveMax(float v) {
#pragma unroll
    for (int off = 32; off > 0; off >>= 1)
        v = fmaxf(v, __shfl_xor(v, off, 64));
    return v;
}

// Block-wide max of v (256 threads = 4 waves), result broadcast to all threads.
// Safe to call repeatedly (leading guard sync). Branches calling it must be
// block-uniform.
__device__ __forceinline__ float blockMaxBcast(float v, float* scratch) {
    float wm = waveMax(v);
    __syncthreads();                       // guard: previous users of scratch done
    if ((threadIdx.x & 63) == 0) scratch[threadIdx.x >> 6] = wm;
    __syncthreads();
    return fmaxf(fmaxf(scratch[0], scratch[1]), fmaxf(scratch[2], scratch[3]));
}

// One-time: Ws = softmax(W, axis=1)
__global__ void kinit(const float* __restrict__ W, float* __restrict__ Ws) {
    int t = threadIdx.x;           // 256 threads
    int m = t >> 4, c = t & 15;
    float rmax = -INFINITY;
#pragma unroll
    for (int j = 0; j < C; j++) rmax = fmaxf(rmax, W[m * C + j]);
    float rsum = 0.f;
#pragma unroll
    for (int j = 0; j < C; j++) rsum += __expf(W[m * C + j] - rmax);
    Ws[m * C + c] = __expf(W[m * C + c] - rmax) / rsum;
}

// K1: Cv[b,c,g] = gamma*lse_s( prod_l (s*V[b, I[c,g,s,l]]) / gamma )
// s = scale from previous iteration's Ry partial maxes (Pm3prev, 256 entries), or 1.
// Per-block max -> Pm1[(b*NCG+cg)*NGT+gt]  (512 partials, no atomics).
__global__ __launch_bounds__(256) void k1(
    const float* __restrict__ Vsrc, const float* __restrict__ Pm3prev,
    const int* __restrict__ I, float* __restrict__ Cv, float* __restrict__ Pm1) {
    __shared__ float Vrow[G];      // 8 KB
    __shared__ float scratch[4];
    const int b = blockIdx.z, cg = blockIdx.y, gt = blockIdx.x;
    const int t = threadIdx.x;

    float s = 1.0f;
    if (Pm3prev) {                 // uniform branch
        float m3 = blockMaxBcast(Pm3prev[t], scratch);
        s = (m3 > 1.0f) ? 1.0f / m3 : 1.0f;
    }

    const float4* V4 = (const float4*)(Vsrc + (size_t)b * G);
    float4* Vr4 = (float4*)Vrow;
#pragma unroll
    for (int j = 0; j < 2; j++) {
        float4 v = V4[t + j * 256];
        v.x *= s; v.y *= s; v.z *= s; v.w *= s;
        Vr4[t + j * 256] = v;
    }
    __syncthreads();

    const int g = gt * 256 + t;
    float ymax = -INFINITY;
#pragma unroll 2
    for (int j = 0; j < 8; j++) {
        const int c = cg * 8 + j;
        const int4* ip = (const int4*)(I + ((size_t)c * G + g) * (S * L));
        int idx[S * L];
#pragma unroll
        for (int q = 0; q < 6; q++) {
            int4 v = ip[q];
            idx[q * 4 + 0] = v.x; idx[q * 4 + 1] = v.y;
            idx[q * 4 + 2] = v.z; idx[q * 4 + 3] = v.w;
        }
        float body[S];
#pragma unroll
        for (int ss = 0; ss < S; ss++)
            body[ss] = Vrow[idx[ss * 3]] * Vrow[idx[ss * 3 + 1]] * Vrow[idx[ss * 3 + 2]];
        float bm = body[0];
#pragma unroll
        for (int ss = 1; ss < S; ss++) bm = fmaxf(bm, body[ss]);
        float sum = 0.f;
#pragma unroll
        for (int ss = 0; ss < S; ss++) sum += __expf((body[ss] - bm) * INV_GAMMA);
        float y = bm + GAMMA * __logf(sum);
        Cv[((size_t)b * C + c) * G + g] = y;
        ymax = fmaxf(ymax, y);
    }

    float wm = waveMax(ymax);
    __syncthreads();
    if ((t & 63) == 0) scratch[t >> 6] = wm;
    __syncthreads();
    if (t == 0)
        Pm1[(b * NCG + cg) * NGT + gt] =
            fmaxf(fmaxf(scratch[0], scratch[1]), fmaxf(scratch[2], scratch[3]));
}

// K2: H[m] = sum_c Ws[m,c]*(s1*Cv[b,c,g]); Hy = gamma*lse_m(H/gamma)
// s1 from Pm1 (512 partials). Per-block max -> Pm2[b*NGT+gt] (256 partials).
__global__ __launch_bounds__(256) void k2(
    const float* __restrict__ Cv, const float* __restrict__ Ws,
    const float* __restrict__ Pm1, float* __restrict__ Hy, float* __restrict__ Pm2) {
    __shared__ float WsL[M * C];
    __shared__ float scratch[4];
    const int b = blockIdx.y, gt = blockIdx.x, t = threadIdx.x;

    WsL[t] = Ws[t];                            // covered by blockMaxBcast's syncs
    float m1 = blockMaxBcast(fmaxf(Pm1[t], Pm1[t + 256]), scratch);
    float s1 = (m1 > 1.0f) ? 1.0f / m1 : 1.0f;

    const int g = gt * 256 + t;
    float cv[C];
#pragma unroll
    for (int c = 0; c < C; c++)
        cv[c] = s1 * Cv[((size_t)b * C + c) * G + g];

    float h[M];
    float hm = -INFINITY;
#pragma unroll
    for (int m = 0; m < M; m++) {
        float acc = 0.f;
#pragma unroll
        for (int c = 0; c < C; c++) acc = fmaf(WsL[m * C + c], cv[c], acc);
        h[m] = acc; hm = fmaxf(hm, acc);
    }
    float sum = 0.f;
#pragma unroll
    for (int m = 0; m < M; m++) sum += __expf((h[m] - hm) * INV_GAMMA);
    float y = hm + GAMMA * __logf(sum);
    Hy[(size_t)b * G + g] = y;

    float wm = waveMax(y);
    __syncthreads();
    if ((t & 63) == 0) scratch[t >> 6] = wm;
    __syncthreads();
    if (t == 0)
        Pm2[b * NGT + gt] =
            fmaxf(fmaxf(scratch[0], scratch[1]), fmaxf(scratch[2], scratch[3]));
}

// K3: Ry = gamma*lse_2(sp*Rprev, s2*Hy). Per-block max -> Pm3[blockIdx.x] (256).
__global__ __launch_bounds__(256) void k3(
    const float* __restrict__ Rprev, const float* __restrict__ Pm3prev,
    const float* __restrict__ Hy, const float* __restrict__ Pm2,
    float* __restrict__ Ry, float* __restrict__ Pm3) {
    __shared__ float scratch[4];
    const int t = threadIdx.x;
    const int i = blockIdx.x * 256 + t;

    float sp = 1.0f;
    if (Pm3prev) {                 // uniform branch
        float m = blockMaxBcast(Pm3prev[t], scratch);
        sp = (m > 1.0f) ? 1.0f / m : 1.0f;
    }
    float m2 = blockMaxBcast(Pm2[t], scratch);
    float s2 = (m2 > 1.0f) ? 1.0f / m2 : 1.0f;

    float Rv = sp * Rprev[i];
    float rv = s2 * Hy[i];
    float a = fmaxf(Rv, rv), d = fminf(Rv, rv);
    float y = a + GAMMA * __logf(1.0f + __expf((d - a) * INV_GAMMA));
    Ry[i] = y;

    float wm = waveMax(y);
    __syncthreads();
    if ((t & 63) == 0) scratch[t >> 6] = wm;
    __syncthreads();
    if (t == 0)
        Pm3[blockIdx.x] =
            fmaxf(fmaxf(scratch[0], scratch[1]), fmaxf(scratch[2], scratch[3]));
}

__global__ void kout(const float* __restrict__ Ry, const float* __restrict__ Pm3,
                     float* __restrict__ out) {
    __shared__ float scratch[4];
    const int t = threadIdx.x;
    const int i = blockIdx.x * 256 + t;
    float m = blockMaxBcast(Pm3[t], scratch);
    float s = (m > 1.0f) ? 1.0f / m : 1.0f;
    out[i] = s * Ry[i];
}

extern "C" void kernel_launch(void* const* d_in, const int* in_sizes, int n_in,
                              void* d_out, int out_size, void* d_ws, size_t ws_size,
                              hipStream_t stream) {
    const float* x = (const float*)d_in[0];   // (B,G)
    const float* W = (const float*)d_in[1];   // (M,C)
    const int*   I = (const int*)d_in[2];     // (C,G,S,L)
    float* out = (float*)d_out;

    float* ws   = (float*)d_ws;
    float* Ws   = ws;                          // 256
    float* Pm1  = ws + 256;                    // 5 * 512
    float* Pm2  = Pm1 + 5 * 512;               // 5 * 256
    float* Pm3  = Pm2 + 5 * 256;               // 5 * 256
    float* Cv   = Pm3 + 5 * 256;               // B*C*G
    float* Hy   = Cv + (size_t)B * C * G;      // B*G
    float* Ry   = Hy + (size_t)B * G;          // B*G

    kinit<<<1, 256, 0, stream>>>(W, Ws);

    const float* V = x;
    const float* p3prev = nullptr;
    for (int it = 0; it < 5; it++) {
        float* pm1 = Pm1 + it * 512;
        float* pm2 = Pm2 + it * 256;
        float* pm3 = Pm3 + it * 256;
        k1<<<dim3(NGT, NCG, B), 256, 0, stream>>>(V, p3prev, I, Cv, pm1);
        k2<<<dim3(NGT, B), 256, 0, stream>>>(Cv, Ws, pm1, Hy, pm2);
        k3<<<dim3((B * G) / 256), 256, 0, stream>>>(V, p3prev, Hy, pm2, Ry, pm3);
        V = Ry;
        p3prev = pm3;
    }
    kout<<<(B * G) / 256, 256, 0, stream>>>(Ry, Pm3 + 4 * 256, out);
}